// Round 13
// baseline (71.208 us; speedup 1.0000x reference)
//
#include <hip/hip_runtime.h>

// Problem constants: B=8, N=2048, M=2048, D=128
#define B_DIM 8
#define N_DIM 2048
#define M_DIM 2048
#define D_DIM 128
#define NT_TILES 2

typedef __bf16 bf16_t;
typedef bf16_t bf16x8 __attribute__((ext_vector_type(8)));
typedef float f32x4 __attribute__((ext_vector_type(4)));

// lgkm-only barrier: never drains vmcnt -> global stores / prefetch loads
// stay in flight across tile boundaries.
__device__ __forceinline__ void lgkm_barrier() {
    asm volatile("s_waitcnt lgkmcnt(0)" ::: "memory");
    __builtin_amdgcn_s_barrier();
}

// ---------------------------------------------------------------------------
// Fused kernel, R6 structure with more wave slack:
//  - B tile staged in LDS (32KB, swizzled granules), as R6.
//  - A fragments loaded DIRECTLY from global f32 (L2-resident) with in-reg
//    bf16 RNE conversion; A row norms from the SAME rounded values via
//    shfl_xor(16/32) cross-h reduction. No A LDS, no extra barrier.
//  - LDS 33KB + launch_bounds(256,3) => 3 blocks/CU (12 waves, was 8).
//  - NT_TILES=2 (grid 1024) => block generations stagger (convoy breaking).
//  - Next-tile B prefetch: first half issued BEFORE stores (counted vmcnt,
//    stores never drained), second half right after stores.
// MFMA operands SWAPPED (mfma(B,A)): out-row = lane&15 (A-row),
// out-col = (lane>>4)*4 + reg (B-row) => contiguous f32x4 stores.
// ---------------------------------------------------------------------------
__global__ __launch_bounds__(256, 3) void fused_dist_kernel(
    const float* __restrict__ L, const float* __restrict__ R,
    float* __restrict__ out)
{
    __shared__ bf16x8 Bls[2048];   // 32 KB
    __shared__ float nBs[128];

    const int tid  = threadIdx.x;
    const int bxg  = blockIdx.x;   // covers NT_TILES bx tiles
    const int by   = blockIdx.y;
    const int bz   = blockIdx.z;
    const int wid  = tid >> 6;
    const int lane = tid & 63;
    const int lr   = lane & 15;
    const int h    = lane >> 4;    // 0..3
    const int r    = tid >> 4;     // staging: row within 16-row group
    const int gran = tid & 15;     // staging: 8-elem chunk

    const float* Rbat  = R + (size_t)bz * M_DIM * D_DIM;
    const float* Abase = L + ((size_t)bz * N_DIM + (size_t)by * 128) * D_DIM;

    // ---- stage B tile 0 (f32 -> bf16 RNE -> LDS swizzled) + B norms
    {
        const float* Bsrc = Rbat + (size_t)(bxg * NT_TILES) * 128 * D_DIM;
        #pragma unroll
        for (int i = 0; i < 8; ++i) {
            int row = i * 16 + r;
            float4 v0 = ((const float4*)Bsrc)[(size_t)row * 32 + gran * 2];
            float4 v1 = ((const float4*)Bsrc)[(size_t)row * 32 + gran * 2 + 1];
            bf16x8 p = { (bf16_t)v0.x, (bf16_t)v0.y, (bf16_t)v0.z, (bf16_t)v0.w,
                         (bf16_t)v1.x, (bf16_t)v1.y, (bf16_t)v1.z, (bf16_t)v1.w };
            Bls[i * 256 + gran * 16 + (r ^ gran)] = p;
            float s = 0.0f;
            #pragma unroll
            for (int j = 0; j < 8; ++j) { float x = (float)p[j]; s = fmaf(x, x, s); }
            s += __shfl_xor(s, 1); s += __shfl_xor(s, 2);
            s += __shfl_xor(s, 4); s += __shfl_xor(s, 8);
            if (gran == 0) nBs[i * 16 + r] = s;
        }
    }

    // ---- A fragments direct from global f32, cvt in reg; norms via shfl
    const int wM   = (wid >> 1) * 64;
    const int wN   = (wid & 1) * 64;
    const int bgrp = (wid & 1) * 4;

    bf16x8 af[4][4];
    float l2v[4];
    #pragma unroll
    for (int mt = 0; mt < 4; ++mt) {
        const int row = wM + mt * 16 + lr;
        float s = 0.0f;
        #pragma unroll
        for (int kk = 0; kk < 4; ++kk) {
            // dims kk*32 + h*8 .. +7 of row (fragment af[mt][kk])
            float4 u0 = ((const float4*)Abase)[(size_t)row * 32 + kk * 8 + h * 2];
            float4 u1 = ((const float4*)Abase)[(size_t)row * 32 + kk * 8 + h * 2 + 1];
            bf16x8 p = { (bf16_t)u0.x, (bf16_t)u0.y, (bf16_t)u0.z, (bf16_t)u0.w,
                         (bf16_t)u1.x, (bf16_t)u1.y, (bf16_t)u1.z, (bf16_t)u1.w };
            af[mt][kk] = p;
            #pragma unroll
            for (int j = 0; j < 8; ++j) { float x = (float)p[j]; s = fmaf(x, x, s); }
        }
        // cross-h reduction: lanes {lr, lr+16, lr+32, lr+48} sum k-slices
        s += __shfl_xor(s, 16);
        s += __shfl_xor(s, 32);
        l2v[mt] = s;   // full bf16-rounded norm of row wM+mt*16+lr
    }

    lgkm_barrier();    // B tile 0 + nBs visible

    // ---- tile loop
    for (int t = 0; t < NT_TILES; ++t) {
        const int bx = bxg * NT_TILES + t;

        // 1. MFMA on current B tile
        f32x4 acc[4][4] = {};
        #pragma unroll
        for (int kk = 0; kk < 4; ++kk) {
            int gr = kk * 4 + h;
            int gi = gr * 16 + (lr ^ gr);
            bf16x8 bfr[4];
            #pragma unroll
            for (int q = 0; q < 4; ++q)
                bfr[q] = Bls[(bgrp + q) * 256 + gi];
            #pragma unroll
            for (int mt = 0; mt < 4; ++mt)
                #pragma unroll
                for (int q = 0; q < 4; ++q)
                    acc[mt][q] = __builtin_amdgcn_mfma_f32_16x16x32_bf16(
                        bfr[q], af[mt][kk], acc[mt][q], 0, 0, 0);
        }

        // 2. prefetch FIRST HALF of next B tile before any stores issue
        //    (vmcnt retires in order: conversion's wait stays counted,
        //     stores never drained)
        float4 pf0[4], pf1[4];
        if (t + 1 < NT_TILES) {
            const float* Bsrc = Rbat + (size_t)(bx + 1) * 128 * D_DIM;
            #pragma unroll
            for (int i = 0; i < 4; ++i) {
                int row = i * 16 + r;
                pf0[i] = ((const float4*)Bsrc)[(size_t)row * 32 + gran * 2];
                pf1[i] = ((const float4*)Bsrc)[(size_t)row * 32 + gran * 2 + 1];
            }
        }

        // 3. epilogue + stores
        f32x4 r2v[4];
        #pragma unroll
        for (int q = 0; q < 4; ++q)
            r2v[q] = *(const f32x4*)&nBs[wN + q * 16 + h * 4];
        const size_t outBase =
            ((size_t)bz * N_DIM + (size_t)by * 128) * M_DIM + (size_t)bx * 128;
        #pragma unroll
        for (int mt = 0; mt < 4; ++mt) {
            const int row_l = wM + mt * 16 + lr;
            const float l2 = l2v[mt];
            float* orow = out + outBase + (size_t)row_l * M_DIM;
            #pragma unroll
            for (int q = 0; q < 4; ++q) {
                f32x4 a = acc[mt][q];
                f32x4 o;
                #pragma unroll
                for (int e = 0; e < 4; ++e) {
                    float d2 = fmaf(-2.0f, a[e], l2 + r2v[q][e]);
                    d2 = fmaxf(d2, 0.0f);
                    float sq = __builtin_amdgcn_sqrtf(d2);
                    o[e] = __builtin_amdgcn_rcpf(1.0f + sq);
                }
                *(f32x4*)(orow + wN + q * 16 + h * 4) = o;
            }
        }

        // 4. restage next B tile (second-half loads issued after stores;
        //    their latency overlaps the first-half cvt+ds_write)
        if (t + 1 < NT_TILES) {
            const float* Bsrc = Rbat + (size_t)(bx + 1) * 128 * D_DIM;
            float4 qf0[4], qf1[4];
            #pragma unroll
            for (int i = 0; i < 4; ++i) {
                int row = (i + 4) * 16 + r;
                qf0[i] = ((const float4*)Bsrc)[(size_t)row * 32 + gran * 2];
                qf1[i] = ((const float4*)Bsrc)[(size_t)row * 32 + gran * 2 + 1];
            }

            lgkm_barrier();    // all waves done reading Bls / nBs

            #pragma unroll
            for (int i = 0; i < 8; ++i) {
                float4 v0 = (i < 4) ? pf0[i & 3] : qf0[i & 3];
                float4 v1 = (i < 4) ? pf1[i & 3] : qf1[i & 3];
                bf16x8 p = { (bf16_t)v0.x, (bf16_t)v0.y, (bf16_t)v0.z, (bf16_t)v0.w,
                             (bf16_t)v1.x, (bf16_t)v1.y, (bf16_t)v1.z, (bf16_t)v1.w };
                Bls[i * 256 + gran * 16 + (r ^ gran)] = p;
                float s = 0.0f;
                #pragma unroll
                for (int j = 0; j < 8; ++j) { float x = (float)p[j]; s = fmaf(x, x, s); }
                s += __shfl_xor(s, 1); s += __shfl_xor(s, 2);
                s += __shfl_xor(s, 4); s += __shfl_xor(s, 8);
                if (gran == 0) nBs[i * 16 + r] = s;
            }

            lgkm_barrier();    // staging visible
        }
    }
}

extern "C" void kernel_launch(void* const* d_in, const int* in_sizes, int n_in,
                              void* d_out, int out_size, void* d_ws, size_t ws_size,
                              hipStream_t stream) {
    const float* L = (const float*)d_in[0];
    const float* R = (const float*)d_in[1];
    float* out = (float*)d_out;

    dim3 grid(M_DIM / (128 * NT_TILES), N_DIM / 128, B_DIM);  // 8 x 16 x 8 = 1024
    dim3 block(256);
    fused_dist_kernel<<<grid, block, 0, stream>>>(L, R, out);
}

// Round 14
// 42.011 us; speedup vs baseline: 1.6950x; 1.6950x over previous
//
#include <hip/hip_runtime.h>

// Problem constants: B=8, N=2048, M=2048, D=128
#define B_DIM 8
#define N_DIM 2048
#define M_DIM 2048
#define D_DIM 128
#define NT_TILES 4

typedef __bf16 bf16_t;
typedef bf16_t bf16x8 __attribute__((ext_vector_type(8)));
typedef float f32x4 __attribute__((ext_vector_type(4)));
typedef float f32x16 __attribute__((ext_vector_type(16)));

// lgkm-only barrier: never drains vmcnt -> global stores / prefetch loads
// stay in flight across tile boundaries.
__device__ __forceinline__ void lgkm_barrier() {
    asm volatile("s_waitcnt lgkmcnt(0)" ::: "memory");
    __builtin_amdgcn_s_barrier();
}

// ---------------------------------------------------------------------------
// R6 structure, but MFMA = 32x32x16 UNSWAPPED so stores are FULL 128B lines.
//
// C/D layout (verified m74/m101): out-col = lane&31, out-row =
// (reg&3) + 8*(reg>>2) + 4*(lane>>5). One scalar store instr = lanes 0-31
// writing 128B contiguous of row X + lanes 32-63 writing 128B of row X+4:
// all write requests are full lines (vs 16x64B half-line scatter of the
// 16x16 swapped layout -> halves TCC write-request count per byte).
//
// A/B fragment layout (32x32x16): lane holds row (lane&31),
// k = (lane>>5)*8 + j  => 16B granule (gran = s*2 + (lane>>5)) of row.
//
// Everything else identical to the 41.9us R6 kernel: per-block A panel
// staged once (bf16 RNE + norms from SAME rounded values), B tile staged
// per bx tile, next-B f32 prefetched into regs BEFORE stores issue (vmcnt
// retires in-order -> store queue never drained), lgkm-only barriers.
// ---------------------------------------------------------------------------
__global__ __launch_bounds__(256, 2) void fused_dist_kernel(
    const float* __restrict__ L, const float* __restrict__ R,
    float* __restrict__ out)
{
    __shared__ bf16x8 Als[2048];   // 32 KB
    __shared__ bf16x8 Bls[2048];   // 32 KB
    __shared__ float nAs[128];
    __shared__ float nBs[128];

    const int tid  = threadIdx.x;
    const int bxg  = blockIdx.x;   // covers NT_TILES bx tiles
    const int by   = blockIdx.y;
    const int bz   = blockIdx.z;
    const int wid  = tid >> 6;
    const int lane = tid & 63;
    const int rA   = lane & 15;    // row within 16-row LDS group
    const int g2   = (lane >> 4) & 1;  // which 16-row group within 32
    const int hi   = lane >> 5;    // 0..1 (K-half / row-offset select)
    const int c32  = lane & 31;    // fragment row/col within 32
    const int r    = tid >> 4;     // staging: row within 16-row group
    const int gran = tid & 15;     // staging: 8-elem chunk

    const float* Asrc = L + ((size_t)bz * N_DIM + (size_t)by * 128) * D_DIM;
    const float* Rbat = R + (size_t)bz * M_DIM * D_DIM;

    // ---- initial stage: A panel (bf16 RNE + norms from SAME rounded values)
    #pragma unroll
    for (int i = 0; i < 8; ++i) {
        int row = i * 16 + r;
        float4 v0 = ((const float4*)Asrc)[(size_t)row * 32 + gran * 2];
        float4 v1 = ((const float4*)Asrc)[(size_t)row * 32 + gran * 2 + 1];
        bf16x8 p = { (bf16_t)v0.x, (bf16_t)v0.y, (bf16_t)v0.z, (bf16_t)v0.w,
                     (bf16_t)v1.x, (bf16_t)v1.y, (bf16_t)v1.z, (bf16_t)v1.w };
        Als[i * 256 + gran * 16 + (r ^ gran)] = p;
        float s = 0.0f;
        #pragma unroll
        for (int j = 0; j < 8; ++j) { float x = (float)p[j]; s = fmaf(x, x, s); }
        s += __shfl_xor(s, 1); s += __shfl_xor(s, 2);
        s += __shfl_xor(s, 4); s += __shfl_xor(s, 8);
        if (gran == 0) nAs[i * 16 + r] = s;
    }
    // ---- initial stage: B tile 0
    {
        const float* Bsrc = Rbat + (size_t)(bxg * NT_TILES) * 128 * D_DIM;
        #pragma unroll
        for (int i = 0; i < 8; ++i) {
            int row = i * 16 + r;
            float4 v0 = ((const float4*)Bsrc)[(size_t)row * 32 + gran * 2];
            float4 v1 = ((const float4*)Bsrc)[(size_t)row * 32 + gran * 2 + 1];
            bf16x8 p = { (bf16_t)v0.x, (bf16_t)v0.y, (bf16_t)v0.z, (bf16_t)v0.w,
                         (bf16_t)v1.x, (bf16_t)v1.y, (bf16_t)v1.z, (bf16_t)v1.w };
            Bls[i * 256 + gran * 16 + (r ^ gran)] = p;
            float s = 0.0f;
            #pragma unroll
            for (int j = 0; j < 8; ++j) { float x = (float)p[j]; s = fmaf(x, x, s); }
            s += __shfl_xor(s, 1); s += __shfl_xor(s, 2);
            s += __shfl_xor(s, 4); s += __shfl_xor(s, 8);
            if (gran == 0) nBs[i * 16 + r] = s;
        }
    }
    lgkm_barrier();

    // ---- wave tile bases: each wave owns 64x64 = 2x2 of 32x32 MFMA tiles
    const int wM = (wid >> 1) * 64;
    const int wN = (wid & 1) * 64;

    // ---- A fragments into registers (Als dead afterwards): af[tm][s]
    bf16x8 af[2][8];
    #pragma unroll
    for (int s = 0; s < 8; ++s) {
        const int gr = s * 2 + hi;           // 16B k-granule
        #pragma unroll
        for (int tm = 0; tm < 2; ++tm) {
            const int grp = (wM >> 4) + tm * 2 + g2;
            af[tm][s] = Als[grp * 256 + gr * 16 + (rA ^ gr)];
        }
    }

    // ---- tile loop
    for (int t = 0; t < NT_TILES; ++t) {
        const int bx = bxg * NT_TILES + t;

        // 1. MFMA on current B tile (8 K-steps of 16)
        f32x16 acc[2][2] = {};
        #pragma unroll
        for (int s = 0; s < 8; ++s) {
            const int gr = s * 2 + hi;
            bf16x8 bfr[2];
            #pragma unroll
            for (int tn = 0; tn < 2; ++tn) {
                const int grp = (wN >> 4) + tn * 2 + g2;
                bfr[tn] = Bls[grp * 256 + gr * 16 + (rA ^ gr)];
            }
            #pragma unroll
            for (int tm = 0; tm < 2; ++tm)
                #pragma unroll
                for (int tn = 0; tn < 2; ++tn)
                    acc[tm][tn] = __builtin_amdgcn_mfma_f32_32x32x16_bf16(
                        af[tm][s], bfr[tn], acc[tm][tn], 0, 0, 0);
        }

        // 2. prefetch next B tile (f32) into regs BEFORE any stores issue
        float4 pf0[8], pf1[8];
        if (t + 1 < NT_TILES) {
            const float* Bsrc = Rbat + (size_t)(bx + 1) * 128 * D_DIM;
            #pragma unroll
            for (int i = 0; i < 8; ++i) {
                int row = i * 16 + r;
                pf0[i] = ((const float4*)Bsrc)[(size_t)row * 32 + gran * 2];
                pf1[i] = ((const float4*)Bsrc)[(size_t)row * 32 + gran * 2 + 1];
            }
        }

        // 3. epilogue + full-line stores
        //    out-row = wM + tm*32 + g*8 + hi*4 + e,  out-col = wN + tn*32 + c32
        const size_t outBase =
            ((size_t)bz * N_DIM + (size_t)by * 128) * M_DIM + (size_t)bx * 128;
        #pragma unroll
        for (int tm = 0; tm < 2; ++tm) {
            #pragma unroll
            for (int tn = 0; tn < 2; ++tn) {
                const int col_l = wN + tn * 32 + c32;
                const float r2 = nBs[col_l];
                float* ocol = out + outBase + col_l;
                #pragma unroll
                for (int g = 0; g < 4; ++g) {
                    const int rowb = wM + tm * 32 + g * 8 + hi * 4;
                    const f32x4 l2q = *(const f32x4*)&nAs[rowb];
                    #pragma unroll
                    for (int e = 0; e < 4; ++e) {
                        float d2 = fmaf(-2.0f, acc[tm][tn][g * 4 + e],
                                        l2q[e] + r2);
                        d2 = fmaxf(d2, 0.0f);
                        float sq = __builtin_amdgcn_sqrtf(d2);
                        ocol[(size_t)(rowb + e) * M_DIM] =
                            __builtin_amdgcn_rcpf(1.0f + sq);
                    }
                }
            }
        }

        // 4. restage next B tile from prefetched regs (lgkm-only barriers)
        if (t + 1 < NT_TILES) {
            lgkm_barrier();                    // all waves done reading Bls/nBs
            #pragma unroll
            for (int i = 0; i < 8; ++i) {
                bf16x8 p = { (bf16_t)pf0[i].x, (bf16_t)pf0[i].y,
                             (bf16_t)pf0[i].z, (bf16_t)pf0[i].w,
                             (bf16_t)pf1[i].x, (bf16_t)pf1[i].y,
                             (bf16_t)pf1[i].z, (bf16_t)pf1[i].w };
                Bls[i * 256 + gran * 16 + (r ^ gran)] = p;
                float s = 0.0f;
                #pragma unroll
                for (int j = 0; j < 8; ++j) { float x = (float)p[j]; s = fmaf(x, x, s); }
                s += __shfl_xor(s, 1); s += __shfl_xor(s, 2);
                s += __shfl_xor(s, 4); s += __shfl_xor(s, 8);
                if (gran == 0) nBs[i * 16 + r] = s;
            }
            lgkm_barrier();                    // staging visible
        }
    }
}

extern "C" void kernel_launch(void* const* d_in, const int* in_sizes, int n_in,
                              void* d_out, int out_size, void* d_ws, size_t ws_size,
                              hipStream_t stream) {
    const float* L = (const float*)d_in[0];
    const float* R = (const float*)d_in[1];
    float* out = (float*)d_out;

    dim3 grid(M_DIM / (128 * NT_TILES), N_DIM / 128, B_DIM);  // 4 x 16 x 8 = 512
    dim3 block(256);
    fused_dist_kernel<<<grid, block, 0, stream>>>(L, R, out);
}

// Round 15
// 41.388 us; speedup vs baseline: 1.7205x; 1.0150x over previous
//
#include <hip/hip_runtime.h>

// Problem constants: B=8, N=2048, M=2048, D=128
#define B_DIM 8
#define N_DIM 2048
#define M_DIM 2048
#define D_DIM 128
#define NT_TILES 4

typedef __bf16 bf16_t;
typedef bf16_t bf16x8 __attribute__((ext_vector_type(8)));
typedef float f32x4 __attribute__((ext_vector_type(4)));
typedef float f32x16 __attribute__((ext_vector_type(16)));

// lgkm-only barrier: never drains vmcnt -> global stores / prefetch loads
// stay in flight across tile boundaries.
__device__ __forceinline__ void lgkm_barrier() {
    asm volatile("s_waitcnt lgkmcnt(0)" ::: "memory");
    __builtin_amdgcn_s_barrier();
}

// ---------------------------------------------------------------------------
// R10 body (32x32x16 MFMA, full-line stores, fused staging, lgkm-only
// barriers, prefetch-before-stores) + XCD-LOCALITY SWIZZLE:
//
// blockIdx round-robins XCDs (w % 8). B_DIM == 8 XCDs, so assign ONE BATCH
// PER XCD: bz = w&7. Per-XCD input working set = L[bz]+R[bz] = 2MB f32,
// fits the 4MB per-XCD L2 -> panel re-reads become L2 hits instead of
// L3/HBM refetches (R8/R9 showed 56-83MB FETCH vs 16.8MB unique input).
// ---------------------------------------------------------------------------
__global__ __launch_bounds__(256, 2) void fused_dist_kernel(
    const float* __restrict__ L, const float* __restrict__ R,
    float* __restrict__ out)
{
    __shared__ bf16x8 Als[2048];   // 32 KB
    __shared__ bf16x8 Bls[2048];   // 32 KB
    __shared__ float nAs[128];
    __shared__ float nBs[128];

    // ---- XCD-locality decode: one batch per XCD
    const int w   = blockIdx.x;    // [0, 512)
    const int bz  = w & 7;         // XCD id (round-robin dispatch)
    const int i   = w >> 3;        // [0, 64) within XCD
    const int bxg = i & 3;         // covers NT_TILES bx tiles
    const int by  = i >> 2;        // [0, 16)

    const int tid  = threadIdx.x;
    const int wid  = tid >> 6;
    const int lane = tid & 63;
    const int rA   = lane & 15;    // row within 16-row LDS group
    const int g2   = (lane >> 4) & 1;  // which 16-row group within 32
    const int hi   = lane >> 5;    // 0..1 (K-half / row-offset select)
    const int c32  = lane & 31;    // fragment row/col within 32
    const int r    = tid >> 4;     // staging: row within 16-row group
    const int gran = tid & 15;     // staging: 8-elem chunk

    const float* Asrc = L + ((size_t)bz * N_DIM + (size_t)by * 128) * D_DIM;
    const float* Rbat = R + (size_t)bz * M_DIM * D_DIM;

    // ---- initial stage: A panel (bf16 RNE + norms from SAME rounded values)
    #pragma unroll
    for (int i2 = 0; i2 < 8; ++i2) {
        int row = i2 * 16 + r;
        float4 v0 = ((const float4*)Asrc)[(size_t)row * 32 + gran * 2];
        float4 v1 = ((const float4*)Asrc)[(size_t)row * 32 + gran * 2 + 1];
        bf16x8 p = { (bf16_t)v0.x, (bf16_t)v0.y, (bf16_t)v0.z, (bf16_t)v0.w,
                     (bf16_t)v1.x, (bf16_t)v1.y, (bf16_t)v1.z, (bf16_t)v1.w };
        Als[i2 * 256 + gran * 16 + (r ^ gran)] = p;
        float s = 0.0f;
        #pragma unroll
        for (int j = 0; j < 8; ++j) { float x = (float)p[j]; s = fmaf(x, x, s); }
        s += __shfl_xor(s, 1); s += __shfl_xor(s, 2);
        s += __shfl_xor(s, 4); s += __shfl_xor(s, 8);
        if (gran == 0) nAs[i2 * 16 + r] = s;
    }
    // ---- initial stage: B tile 0
    {
        const float* Bsrc = Rbat + (size_t)(bxg * NT_TILES) * 128 * D_DIM;
        #pragma unroll
        for (int i2 = 0; i2 < 8; ++i2) {
            int row = i2 * 16 + r;
            float4 v0 = ((const float4*)Bsrc)[(size_t)row * 32 + gran * 2];
            float4 v1 = ((const float4*)Bsrc)[(size_t)row * 32 + gran * 2 + 1];
            bf16x8 p = { (bf16_t)v0.x, (bf16_t)v0.y, (bf16_t)v0.z, (bf16_t)v0.w,
                         (bf16_t)v1.x, (bf16_t)v1.y, (bf16_t)v1.z, (bf16_t)v1.w };
            Bls[i2 * 256 + gran * 16 + (r ^ gran)] = p;
            float s = 0.0f;
            #pragma unroll
            for (int j = 0; j < 8; ++j) { float x = (float)p[j]; s = fmaf(x, x, s); }
            s += __shfl_xor(s, 1); s += __shfl_xor(s, 2);
            s += __shfl_xor(s, 4); s += __shfl_xor(s, 8);
            if (gran == 0) nBs[i2 * 16 + r] = s;
        }
    }
    lgkm_barrier();

    // ---- wave tile bases: each wave owns 64x64 = 2x2 of 32x32 MFMA tiles
    const int wM = (wid >> 1) * 64;
    const int wN = (wid & 1) * 64;

    // ---- A fragments into registers (Als dead afterwards): af[tm][s]
    bf16x8 af[2][8];
    #pragma unroll
    for (int s = 0; s < 8; ++s) {
        const int gr = s * 2 + hi;           // 16B k-granule
        #pragma unroll
        for (int tm = 0; tm < 2; ++tm) {
            const int grp = (wM >> 4) + tm * 2 + g2;
            af[tm][s] = Als[grp * 256 + gr * 16 + (rA ^ gr)];
        }
    }

    // ---- tile loop
    for (int t = 0; t < NT_TILES; ++t) {
        const int bx = bxg * NT_TILES + t;

        // 1. MFMA on current B tile (8 K-steps of 16)
        f32x16 acc[2][2] = {};
        #pragma unroll
        for (int s = 0; s < 8; ++s) {
            const int gr = s * 2 + hi;
            bf16x8 bfr[2];
            #pragma unroll
            for (int tn = 0; tn < 2; ++tn) {
                const int grp = (wN >> 4) + tn * 2 + g2;
                bfr[tn] = Bls[grp * 256 + gr * 16 + (rA ^ gr)];
            }
            #pragma unroll
            for (int tm = 0; tm < 2; ++tm)
                #pragma unroll
                for (int tn = 0; tn < 2; ++tn)
                    acc[tm][tn] = __builtin_amdgcn_mfma_f32_32x32x16_bf16(
                        af[tm][s], bfr[tn], acc[tm][tn], 0, 0, 0);
        }

        // 2. prefetch next B tile (f32) into regs BEFORE any stores issue
        float4 pf0[8], pf1[8];
        if (t + 1 < NT_TILES) {
            const float* Bsrc = Rbat + (size_t)(bx + 1) * 128 * D_DIM;
            #pragma unroll
            for (int i2 = 0; i2 < 8; ++i2) {
                int row = i2 * 16 + r;
                pf0[i2] = ((const float4*)Bsrc)[(size_t)row * 32 + gran * 2];
                pf1[i2] = ((const float4*)Bsrc)[(size_t)row * 32 + gran * 2 + 1];
            }
        }

        // 3. epilogue + full-line stores
        //    out-row = wM + tm*32 + g*8 + hi*4 + e,  out-col = wN + tn*32 + c32
        const size_t outBase =
            ((size_t)bz * N_DIM + (size_t)by * 128) * M_DIM + (size_t)bx * 128;
        #pragma unroll
        for (int tm = 0; tm < 2; ++tm) {
            #pragma unroll
            for (int tn = 0; tn < 2; ++tn) {
                const int col_l = wN + tn * 32 + c32;
                const float r2 = nBs[col_l];
                float* ocol = out + outBase + col_l;
                #pragma unroll
                for (int g = 0; g < 4; ++g) {
                    const int rowb = wM + tm * 32 + g * 8 + hi * 4;
                    const f32x4 l2q = *(const f32x4*)&nAs[rowb];
                    #pragma unroll
                    for (int e = 0; e < 4; ++e) {
                        float d2 = fmaf(-2.0f, acc[tm][tn][g * 4 + e],
                                        l2q[e] + r2);
                        d2 = fmaxf(d2, 0.0f);
                        float sq = __builtin_amdgcn_sqrtf(d2);
                        ocol[(size_t)(rowb + e) * M_DIM] =
                            __builtin_amdgcn_rcpf(1.0f + sq);
                    }
                }
            }
        }

        // 4. restage next B tile from prefetched regs (lgkm-only barriers)
        if (t + 1 < NT_TILES) {
            lgkm_barrier();                    // all waves done reading Bls/nBs
            #pragma unroll
            for (int i2 = 0; i2 < 8; ++i2) {
                bf16x8 p = { (bf16_t)pf0[i2].x, (bf16_t)pf0[i2].y,
                             (bf16_t)pf0[i2].z, (bf16_t)pf0[i2].w,
                             (bf16_t)pf1[i2].x, (bf16_t)pf1[i2].y,
                             (bf16_t)pf1[i2].z, (bf16_t)pf1[i2].w };
                Bls[i2 * 256 + gran * 16 + (r ^ gran)] = p;
                float s = 0.0f;
                #pragma unroll
                for (int j = 0; j < 8; ++j) { float x = (float)p[j]; s = fmaf(x, x, s); }
                s += __shfl_xor(s, 1); s += __shfl_xor(s, 2);
                s += __shfl_xor(s, 4); s += __shfl_xor(s, 8);
                if (gran == 0) nBs[i2 * 16 + r] = s;
            }
            lgkm_barrier();                    // staging visible
        }
    }
}

extern "C" void kernel_launch(void* const* d_in, const int* in_sizes, int n_in,
                              void* d_out, int out_size, void* d_ws, size_t ws_size,
                              hipStream_t stream) {
    const float* L = (const float*)d_in[0];
    const float* R = (const float*)d_in[1];
    float* out = (float*)d_out;

    // 1D grid: w&7 selects XCD (round-robin) == batch; 64 blocks per XCD.
    dim3 grid(512, 1, 1);
    dim3 block(256);
    fused_dist_kernel<<<grid, block, 0, stream>>>(L, R, out);
}